// Round 1
// baseline (1113.446 us; speedup 1.0000x reference)
//
#include <hip/hip_runtime.h>

// ---------------------------------------------------------------------------
// TrajectoryDecoder: B=4096, F=256, H=256, M=3, T=30 (T read from device)
// out = [trajectories (B,M,T,2) fp32][mode_probs (B,M) fp32]
// R15: R14 structure, MFMA shape 16x16x32 -> 32x32x16. Wave owns exactly 32
// cols per gate, so a 32-wide B-tile fits 1:1: halves MFMA instruction count
// (768->384/wave/step), +15% MFMA rate (2382 vs 2075 TF ubench), A-frag regs
// 32->16, and epilogue LDS writes become 32-consecutive-col (2 lanes/bank,
// conflict-free). Accumulators stay 128 regs (8x f32x16). Same ws tile
// count/regions; prep reordered for the 32x32x16 B-fragment layout.
// Spill-free discipline kept: merged rz+n, #pragma unroll 1 K-loops,
// running pointers, h0 double-buffered (4 barriers/step).
// ---------------------------------------------------------------------------

typedef __attribute__((ext_vector_type(8))) short bf16x8;
typedef __attribute__((ext_vector_type(16))) float f32x16;

__device__ __forceinline__ short f2bf(float f) {
    unsigned u = __builtin_bit_cast(unsigned, f);
    unsigned r = (u + 0x7fffu + ((u >> 16) & 1u)) >> 16;
    return (short)r;
}
__device__ __forceinline__ float bf2f(short s) {
    unsigned u = ((unsigned)(unsigned short)s) << 16;
    return __builtin_bit_cast(float, u);
}
__device__ __forceinline__ float fast_sigmoid(float x) {
    x = fminf(fmaxf(x, -30.f), 30.f);
    float e = __builtin_amdgcn_exp2f(x * -1.442695041f);
    return __builtin_amdgcn_rcpf(1.f + e);
}
__device__ __forceinline__ float fast_tanh(float x) {
    x = fminf(fmaxf(x, -15.f), 15.f);
    float e = __builtin_amdgcn_exp2f(x * -2.885390082f);
    return (1.f - e) * __builtin_amdgcn_rcpf(1.f + e);
}

// ---------------------------------------------------------------------------
// Weight prep: fp32 -> bf16, 32x32x16 B-fragment consumption order.
// B-tile (1KB = 16k x 32cols): lane L holds B[k0+(L>>5)*8+j][cb+(L&31)],
// i.e. src = w[cb+(L&31)][k0+(L>>5)*8+j] (8 contiguous k per lane).
// Regions (1KB blocks), per (m,w8):
//   P0  [0,1152):    w_hh0: 48 = [rz: ks*2+t (32)][hn: 32+ks (16)]
//   P1  [1152,3456): 96 = [ih1 rz: ks*2+t (32)][hh1 rz: 32+ks*2+t (32)]
//                         [ih1 xn: 64+ks (16)][hh1 hn: 80+ks (16)]
//   PC  [3456,4608): w_ih0[:,2:258]: 48 = [rz: ks*2+t (32)][xn: 32+ks (16)]
// ks in [0,16) is the K=16 chunk index; t in {0=r,1=z} -> gate row base t*256.
// ---------------------------------------------------------------------------
__global__ void prep_kernel(const float* __restrict__ w_ih0,
                            const float* __restrict__ w_hh0,
                            const float* __restrict__ w_ih1,
                            const float* __restrict__ w_hh1,
                            short* __restrict__ ws) {
    int bid = blockIdx.x;
    int L = threadIdx.x;
    const float* src;
    int srcRowLen, colBase, m, w, ks, gb;
    if (bid < 1152) {
        int idx = bid, mw = idx / 48, blk = idx % 48;
        m = mw / 8; w = mw % 8;
        if (blk < 32) { ks = blk >> 1; gb = (blk & 1) * 256; }
        else { ks = blk - 32; gb = 512; }
        src = w_hh0 + (size_t)m * 768 * 256; srcRowLen = 256; colBase = 0;
    } else if (bid < 3456) {
        int idx = bid - 1152, mw = idx / 96, blk = idx % 96;
        m = mw / 8; w = mw % 8;
        int half;
        if (blk < 32)      { half = 0; ks = blk >> 1;        gb = (blk & 1) * 256; }
        else if (blk < 64) { half = 1; ks = (blk - 32) >> 1; gb = (blk & 1) * 256; }
        else if (blk < 80) { half = 0; ks = blk - 64;        gb = 512; }
        else               { half = 1; ks = blk - 80;        gb = 512; }
        src = (half ? w_hh1 : w_ih1) + (size_t)m * 768 * 256;
        srcRowLen = 256; colBase = 0;
    } else {
        int idx = bid - 3456, mw = idx / 48, blk = idx % 48;
        m = mw / 8; w = mw % 8;
        if (blk < 32) { ks = blk >> 1; gb = (blk & 1) * 256; }
        else { ks = blk - 32; gb = 512; }
        src = w_ih0 + (size_t)m * 768 * 258; srcRowLen = 258; colBase = 2;
    }
    int row = gb + 32 * w + (L & 31);
    int col0 = colBase + ks * 16 + (L >> 5) * 8;
    short* dst = ws + (size_t)bid * 512 + L * 8;
    const float* s = src + (size_t)row * srcRowLen + col0;
#pragma unroll
    for (int j = 0; j < 8; ++j) dst[j] = f2bf(s[j]);
}

// ---------------------------------------------------------------------------
// Mode-probability MLP
// ---------------------------------------------------------------------------
__global__ __launch_bounds__(256) void modeprobs_kernel(
    const float* __restrict__ ctx, const float* __restrict__ w1,
    const float* __restrict__ b1, const float* __restrict__ w2,
    const float* __restrict__ b2, float* __restrict__ out,
    long probs_off) {
    __shared__ float w1s[64 * 256];
    int tid = threadIdx.x;
    int j = tid & 63;
    int rsub = tid >> 6;
#pragma unroll
    for (int i = 0; i < 64; ++i) w1s[tid + i * 256] = w1[tid + i * 256];
    float b1v = b1[j];
    float w2v0 = w2[j], w2v1 = w2[64 + j], w2v2 = w2[128 + j];
    float b20 = b2[0], b21 = b2[1], b22 = b2[2];
    __syncthreads();
    for (int c = 0; c < 16; ++c) {
        int brow = blockIdx.x * 64 + c * 4 + rsub;
        const float* crow = ctx + (size_t)brow * 256;
        float accv = b1v;
#pragma unroll 8
        for (int k = 0; k < 256; ++k) {
            int kk = (k + j) & 255;
            accv += w1s[j * 256 + kk] * crow[kk];
        }
        float h = fmaxf(accv, 0.f);
        float l0 = h * w2v0, l1 = h * w2v1, l2 = h * w2v2;
#pragma unroll
        for (int s = 1; s < 64; s <<= 1) {
            l0 += __shfl_xor(l0, s);
            l1 += __shfl_xor(l1, s);
            l2 += __shfl_xor(l2, s);
        }
        if (j == 0) {
            l0 += b20; l1 += b21; l2 += b22;
            float mx = fmaxf(l0, fmaxf(l1, l2));
            float e0 = __builtin_amdgcn_exp2f((l0 - mx) * 1.442695041f);
            float e1 = __builtin_amdgcn_exp2f((l1 - mx) * 1.442695041f);
            float e2 = __builtin_amdgcn_exp2f((l2 - mx) * 1.442695041f);
            float inv = 1.f / (e0 + e1 + e2);
            out[probs_off + (size_t)brow * 3 + 0] = e0 * inv;
            out[probs_off + (size_t)brow * 3 + 1] = e1 * inv;
            out[probs_off + (size_t)brow * 3 + 2] = e2 * inv;
        }
    }
}

// ---------------------------------------------------------------------------
// Persistent GRU decoder. Block = 64 batch rows x 1 mode; 512 threads
// (8 waves, wave w owns cols {32w..32w+31} of each gate; one col per lane).
// 32x32x16 MFMA: A-frag row = rt*32+(lane&31), k = ks*16+(lane>>5)*8;
// C/D: col = lane&31, row = (reg&3)+8*(reg>>2)+4*(lane>>5).  h0 dbuf.
// ---------------------------------------------------------------------------
__global__ __launch_bounds__(512, 2) void decoder_kernel(
    const float* __restrict__ context,
    const float* __restrict__ w_ih0_f,   // (3,768,258): pos-weight cols 0..1
    const float* __restrict__ b_ih0, const float* __restrict__ b_hh0,
    const float* __restrict__ b_ih1, const float* __restrict__ b_hh1,
    const float* __restrict__ out_w, const float* __restrict__ out_b,
    const short* __restrict__ ws, float* __restrict__ out,
    const int* __restrict__ pT, int ntiles) {
    __shared__ short ctxS[64 * 264];   // read-only after init
    __shared__ short h0a[64 * 264], h0b[64 * 264];  // double-buffered h0
    __shared__ short h1s[64 * 264];
    __shared__ float posD[128];
    __shared__ float owl[512];
    __shared__ float cwp0[768], cwp1[768];  // w_ih0[:,0], w_ih0[:,1]
    __shared__ float cbA[512];              // L0 rz: b_ih0+b_hh0
    __shared__ float cbXn[256];             // L0 n:  b_ih0
    __shared__ float cbh0n[256];            // L0 n:  b_hh0
    __shared__ float cb1A[512];             // L1 rz: b_ih1+b_hh1
    __shared__ float cb1X[256];             // L1 n:  b_ih1
    __shared__ float cb1H[256];             // L1 n:  b_hh1

    const int bid = blockIdx.x;
    const int xcd = bid & 7, slot = bid >> 3;
    int mode, xl, nx;
    if (xcd < 3)      { mode = 0; xl = xcd;     nx = 3; }
    else if (xcd < 6) { mode = 1; xl = xcd - 3; nx = 3; }
    else              { mode = 2; xl = xcd - 6; nx = 2; }
    const int g = slot * nx + xl;
    if (g >= ntiles) return;
    const int m = mode;
    const int b0 = g * 64;

    const int T = *pT;
    const int tid = threadIdx.x;
    const int lane = tid & 63, w = tid >> 6;
    const int l31 = lane & 31, lhi = lane >> 5;
    const int c = 32 * w + l31;      // this lane's gate column (per gate)

    if (tid < 128) posD[tid] = 0.f;
    owl[tid] = out_w[m * 512 + tid];
    if (tid < 512) {
        cbA[tid] = b_ih0[m * 768 + tid] + b_hh0[m * 768 + tid];
        cb1A[tid] = b_ih1[m * 768 + tid] + b_hh1[m * 768 + tid];
    }
    if (tid < 256) {
        cbXn[tid] = b_ih0[m * 768 + 512 + tid];
        cbh0n[tid] = b_hh0[m * 768 + 512 + tid];
        cb1X[tid] = b_ih1[m * 768 + 512 + tid];
        cb1H[tid] = b_hh1[m * 768 + 512 + tid];
    }
    for (int cc = tid; cc < 768; cc += 512) {
        cwp0[cc] = w_ih0_f[((size_t)m * 768 + cc) * 258 + 0];
        cwp1[cc] = w_ih0_f[((size_t)m * 768 + cc) * 258 + 1];
    }
#pragma unroll
    for (int i = 0; i < 32; ++i) {
        int idx = tid + i * 512;
        int r = idx >> 8, k = idx & 255;
        short v = f2bf(context[(size_t)(b0 + r) * 256 + k]);
        ctxS[r * 264 + k] = v;
        h0a[r * 264 + k] = v;
        h1s[r * 264 + k] = v;
    }
    const float ob0v = out_b[m * 2 + 0], ob1v = out_b[m * 2 + 1];

    const short* p0w = ws + ((size_t)(m * 8 + w) * 48) * 512 + lane * 8;
    const short* p1w = ws + (size_t)1152 * 512 + ((size_t)(m * 8 + w) * 96) * 512 + lane * 8;
    const short* pcw = ws + (size_t)3456 * 512 + ((size_t)(m * 8 + w) * 48) * 512 + lane * 8;

    __syncthreads();

    float cum0 = 0.f, cum1 = 0.f;

    for (int st = 0; st < T; ++st) {
        const short* h0c = (st & 1) ? h0b : h0a;   // current h0
        short* h0n_ = (st & 1) ? h0a : h0b;        // next h0 (no WAR hazard)

        // ======== layer 0 (merged rz+n, unroll-1 K-loop) ========
        {
            f32x16 arz[2][2], axn[2], ahn[2];
            const float bAr = cbA[c], bAz = cbA[256 + c];
            const float bXnv = cbXn[c], bh0nv = cbh0n[c];
            const float w0r = cwp0[c], w1r = cwp1[c];
            const float w0z = cwp0[256 + c], w1z = cwp1[256 + c];
            const float w0n = cwp0[512 + c], w1n = cwp1[512 + c];
#pragma unroll
            for (int rt = 0; rt < 2; ++rt)
#pragma unroll
                for (int gq = 0; gq < 4; ++gq)
#pragma unroll
                    for (int q = 0; q < 4; ++q) {
                        int reg = gq * 4 + q;
                        int row = rt * 32 + q + 8 * gq + 4 * lhi;
                        float px = posD[row * 2], py = posD[row * 2 + 1];
                        arz[0][rt][reg] = bAr + px * w0r + py * w1r;
                        arz[1][rt][reg] = bAz + px * w0z + py * w1z;
                        axn[rt][reg] = bXnv + px * w0n + py * w1n;
                        ahn[rt][reg] = bh0nv;
                    }
            const short* bcr = pcw;              // ctx rz: 2 tiles/ks
            const short* bcn = pcw + 32 * 512;   // ctx xn: 1 tile/ks
            const short* b0r = p0w;              // hh0 rz: 2 tiles/ks
            const short* b0n = p0w + 32 * 512;   // hh0 hn: 1 tile/ks
#pragma unroll 1
            for (int ks = 0; ks < 16; ++ks) {
                bf16x8 ac[2], ah[2];
#pragma unroll
                for (int rt = 0; rt < 2; ++rt) {
                    ac[rt] = *reinterpret_cast<const bf16x8*>(
                        ctxS + (rt * 32 + l31) * 264 + ks * 16 + lhi * 8);
                    ah[rt] = *reinterpret_cast<const bf16x8*>(
                        h0c + (rt * 32 + l31) * 264 + ks * 16 + lhi * 8);
                }
#pragma unroll
                for (int t = 0; t < 2; ++t) {
                    bf16x8 b = *reinterpret_cast<const bf16x8*>(bcr + t * 512);
#pragma unroll
                    for (int rt = 0; rt < 2; ++rt)
                        arz[t][rt] = __builtin_amdgcn_mfma_f32_32x32x16_bf16(
                            ac[rt], b, arz[t][rt], 0, 0, 0);
                }
                {
                    bf16x8 b = *reinterpret_cast<const bf16x8*>(bcn);
#pragma unroll
                    for (int rt = 0; rt < 2; ++rt)
                        axn[rt] = __builtin_amdgcn_mfma_f32_32x32x16_bf16(
                            ac[rt], b, axn[rt], 0, 0, 0);
                }
#pragma unroll
                for (int t = 0; t < 2; ++t) {
                    bf16x8 b = *reinterpret_cast<const bf16x8*>(b0r + t * 512);
#pragma unroll
                    for (int rt = 0; rt < 2; ++rt)
                        arz[t][rt] = __builtin_amdgcn_mfma_f32_32x32x16_bf16(
                            ah[rt], b, arz[t][rt], 0, 0, 0);
                }
                {
                    bf16x8 b = *reinterpret_cast<const bf16x8*>(b0n);
#pragma unroll
                    for (int rt = 0; rt < 2; ++rt)
                        ahn[rt] = __builtin_amdgcn_mfma_f32_32x32x16_bf16(
                            ah[rt], b, ahn[rt], 0, 0, 0);
                }
                bcr += 2 * 512;
                bcn += 512;
                b0r += 2 * 512;
                b0n += 512;
            }
            // no barrier: epilogue writes h0n_ (other buffer), no WAR hazard
#pragma unroll
            for (int rt = 0; rt < 2; ++rt)
#pragma unroll
                for (int gq = 0; gq < 4; ++gq)
#pragma unroll
                    for (int q = 0; q < 4; ++q) {
                        int reg = gq * 4 + q;
                        int row = rt * 32 + q + 8 * gq + 4 * lhi;
                        float rr = fast_sigmoid(arz[0][rt][reg]);
                        float zz = fast_sigmoid(arz[1][rt][reg]);
                        float nn = fast_tanh(axn[rt][reg] + rr * ahn[rt][reg]);
                        float hold = bf2f(h0c[row * 264 + c]);
                        h0n_[row * 264 + c] = f2bf((1.f - zz) * nn + zz * hold);
                    }
        }
        __syncthreads();  // B1: h0' visible

        // ======== layer 1 (merged rz+n, unroll-1 K-loop) ========
        {
            f32x16 arz[2][2], axn[2], ahn[2];
            const float bAr = cb1A[c], bAz = cb1A[256 + c];
            const float bXv = cb1X[c], bHv = cb1H[c];
#pragma unroll
            for (int rt = 0; rt < 2; ++rt)
#pragma unroll
                for (int reg = 0; reg < 16; ++reg) {
                    arz[0][rt][reg] = bAr;
                    arz[1][rt][reg] = bAz;
                    axn[rt][reg] = bXv;
                    ahn[rt][reg] = bHv;
                }
            const short* bq0 = p1w;            // w_ih1 rz (A = h0')
            const short* bq1 = p1w + 32 * 512; // w_hh1 rz (A = h1)
            const short* bx = p1w + 64 * 512;  // w_ih1 xn (A = h0')
            const short* bh = p1w + 80 * 512;  // w_hh1 hn (A = h1)
#pragma unroll 1
            for (int ks = 0; ks < 16; ++ks) {
                bf16x8 a0[2], a1[2];
#pragma unroll
                for (int rt = 0; rt < 2; ++rt) {
                    a0[rt] = *reinterpret_cast<const bf16x8*>(
                        h0n_ + (rt * 32 + l31) * 264 + ks * 16 + lhi * 8);
                    a1[rt] = *reinterpret_cast<const bf16x8*>(
                        h1s + (rt * 32 + l31) * 264 + ks * 16 + lhi * 8);
                }
#pragma unroll
                for (int t = 0; t < 2; ++t) {
                    bf16x8 b = *reinterpret_cast<const bf16x8*>(bq0 + t * 512);
#pragma unroll
                    for (int rt = 0; rt < 2; ++rt)
                        arz[t][rt] = __builtin_amdgcn_mfma_f32_32x32x16_bf16(
                            a0[rt], b, arz[t][rt], 0, 0, 0);
                }
                {
                    bf16x8 b = *reinterpret_cast<const bf16x8*>(bx);
#pragma unroll
                    for (int rt = 0; rt < 2; ++rt)
                        axn[rt] = __builtin_amdgcn_mfma_f32_32x32x16_bf16(
                            a0[rt], b, axn[rt], 0, 0, 0);
                }
#pragma unroll
                for (int t = 0; t < 2; ++t) {
                    bf16x8 b = *reinterpret_cast<const bf16x8*>(bq1 + t * 512);
#pragma unroll
                    for (int rt = 0; rt < 2; ++rt)
                        arz[t][rt] = __builtin_amdgcn_mfma_f32_32x32x16_bf16(
                            a1[rt], b, arz[t][rt], 0, 0, 0);
                }
                {
                    bf16x8 b = *reinterpret_cast<const bf16x8*>(bh);
#pragma unroll
                    for (int rt = 0; rt < 2; ++rt)
                        ahn[rt] = __builtin_amdgcn_mfma_f32_32x32x16_bf16(
                            a1[rt], b, ahn[rt], 0, 0, 0);
                }
                bq0 += 2 * 512;
                bq1 += 2 * 512;
                bx += 512;
                bh += 512;
            }
            __syncthreads();  // B2: all h1 reads complete
#pragma unroll
            for (int rt = 0; rt < 2; ++rt)
#pragma unroll
                for (int gq = 0; gq < 4; ++gq)
#pragma unroll
                    for (int q = 0; q < 4; ++q) {
                        int reg = gq * 4 + q;
                        int row = rt * 32 + q + 8 * gq + 4 * lhi;
                        float rr = fast_sigmoid(arz[0][rt][reg]);
                        float zz = fast_sigmoid(arz[1][rt][reg]);
                        float nn = fast_tanh(axn[rt][reg] + rr * ahn[rt][reg]);
                        float hold = bf2f(h1s[row * 264 + c]);
                        h1s[row * 264 + c] = f2bf((1.f - zz) * nn + zz * hold);
                    }
        }
        __syncthreads();  // B3: h1' visible

        // ---------------- delta = h1' @ ow.T + ob ; cumsum -> out
        {
            int brow = tid >> 3, p = tid & 7;
            float d0 = 0.f, d1 = 0.f;
#pragma unroll
            for (int j = 0; j < 4; ++j) {
                int cb = ((p + brow) & 7) * 8 + j * 64;
                bf16x8 hv8 = *reinterpret_cast<const bf16x8*>(h1s + brow * 264 + cb);
#pragma unroll
                for (int i = 0; i < 8; ++i) {
                    float hv = bf2f(hv8[i]);
                    d0 += hv * owl[cb + i];
                    d1 += hv * owl[256 + cb + i];
                }
            }
            d0 += __shfl_xor(d0, 1); d0 += __shfl_xor(d0, 2); d0 += __shfl_xor(d0, 4);
            d1 += __shfl_xor(d1, 1); d1 += __shfl_xor(d1, 2); d1 += __shfl_xor(d1, 4);
            d0 += ob0v;
            d1 += ob1v;
            if (p == 0) {
                cum0 += d0;
                cum1 += d1;
                size_t o = (((size_t)(b0 + brow) * 3 + m) * (size_t)T + st) * 2;
                out[o] = cum0;
                out[o + 1] = cum1;
                posD[brow * 2] = d0;
                posD[brow * 2 + 1] = d1;
            }
        }
        __syncthreads();  // B4: posD ready
    }
}

extern "C" void kernel_launch(void* const* d_in, const int* in_sizes, int n_in,
                              void* d_out, int out_size, void* d_ws, size_t ws_size,
                              hipStream_t stream) {
    const float* context = (const float*)d_in[0];
    const float* mp_w1 = (const float*)d_in[1];
    const float* mp_b1 = (const float*)d_in[2];
    const float* mp_w2 = (const float*)d_in[3];
    const float* mp_b2 = (const float*)d_in[4];
    const float* w_ih0 = (const float*)d_in[5];
    const float* w_hh0 = (const float*)d_in[6];
    const float* b_ih0 = (const float*)d_in[7];
    const float* b_hh0 = (const float*)d_in[8];
    const float* w_ih1 = (const float*)d_in[9];
    const float* w_hh1 = (const float*)d_in[10];
    const float* b_ih1 = (const float*)d_in[11];
    const float* b_hh1 = (const float*)d_in[12];
    const float* out_w = (const float*)d_in[13];
    const float* out_b = (const float*)d_in[14];
    const int* pT = (const int*)d_in[15];
    float* out = (float*)d_out;
    short* ws = (short*)d_ws;

    const int B = in_sizes[0] / 256;                      // 4096
    const int ntiles = B / 64;                            // 64
    const long probs_off = (long)out_size - (long)B * 3;

    prep_kernel<<<4608, 64, 0, stream>>>(w_ih0, w_hh0, w_ih1, w_hh1, ws);
    modeprobs_kernel<<<B / 64, 256, 0, stream>>>(context, mp_w1, mp_b1, mp_w2,
                                                 mp_b2, out, probs_off);
    const int nslots = (ntiles + 1) / 2;
    decoder_kernel<<<8 * nslots, 512, 0, stream>>>(
        context, w_ih0, b_ih0, b_hh0, b_ih1, b_hh1, out_w, out_b, ws, out, pT,
        ntiles);
}